// Round 5
// baseline (409.076 us; speedup 1.0000x reference)
//
#include <hip/hip_runtime.h>

typedef unsigned int u32;
typedef unsigned short u16;
typedef unsigned long long u64;

// Problem constants
#define NPTS 65536
#define PCLD 2048
#define KNN 20
#define HD 128
#define HD2 256

typedef __attribute__((ext_vector_type(8))) short bf16x8;   // 8 bf16 = 4 VGPRs (A/B frag)
typedef __attribute__((ext_vector_type(4))) float f32x4;    // C/D frag

__device__ __forceinline__ float bf2f(u16 h) { return __uint_as_float(((u32)h) << 16); }
__device__ __forceinline__ u16 f2bf(float f) {
    u32 u = __float_as_uint(f);
    u32 r = (u + 0x7FFFu + ((u >> 16) & 1u)) >> 16;  // RNE
    return (u16)r;
}

// ---------------------------------------------------------------------------
// Pack kernel: x [N][3] fp32 -> pts4 [N] float4 (x,y,z,sq), exact RN chain
// sq = RN(RN(x^2+y^2)+z^2)  -- matches np's row-norm computation.
// ---------------------------------------------------------------------------
__global__ __launch_bounds__(256) void pack_kernel(const float* __restrict__ x,
                                                   float4* __restrict__ pts4) {
    int i = blockIdx.x * 256 + threadIdx.x;
    float a = x[3 * i], b = x[3 * i + 1], c = x[3 * i + 2];
    float sq = __fadd_rn(__fadd_rn(__fmul_rn(a, a), __fmul_rn(b, b)), __fmul_rn(c, c));
    pts4[i] = make_float4(a, b, c, sq);
}

// ---------------------------------------------------------------------------
// Weight prep: fp32 -> bf16 + transpose.
// ---------------------------------------------------------------------------
__global__ __launch_bounds__(256) void prep_kernel(
    const float* __restrict__ W1_0, const float* __restrict__ W2_0,
    const float* __restrict__ W1_1, const float* __restrict__ W2_1,
    u16* __restrict__ W1_0T, u16* __restrict__ W2_0T,
    u16* __restrict__ W1_1T, u16* __restrict__ W2_1T) {
    int id = blockIdx.x * 256 + threadIdx.x;   // 4 * 32768 threads
    int m = id >> 15, e = id & 32767;
    if (m == 0)      { int n = e >> 7, k = e & 127; W1_0T[e] = f2bf(W1_0[k * 256 + n]); }
    else if (m == 1) { int n = e >> 8, k = e & 255; W2_0T[e] = f2bf(W2_0[k * 128 + n]); }
    else if (m == 2) { int n = e >> 7, k = e & 127; W1_1T[e] = f2bf(W1_1[k * 256 + n]); }
    else             { int n = e >> 8, k = e & 255; W2_1T[e] = f2bf(W2_1[k * 128 + n]); }
}

// ---------------------------------------------------------------------------
// kNN v4: 1 thread = 1 query, S=1 (no candidate split — R4 showed insert work
// inflates 1.75x with S=2). Candidate broadcast via WAVE-UNIFORM vector loads
// (global_load_dwordx4, all lanes same address -> L1 broadcast, 1 instr/cand
// vs 4 readlanes) with an 8-deep register double-buffer. LDS keeps a cloud
// copy ONLY for the divergent drain re-reads. Top-20 as sorted u64 monotone
// (dist,idx) keys -> exact top_k tie semantics.
// Distance replicates np fp32 op order:
//   dot = fma(z,zq, fma(y,yq, RN(x*xq))); d = RN(RN(sq_q+sq_c) - RN(2*dot))
// ---------------------------------------------------------------------------
__global__ __launch_bounds__(256) void knn_kernel(const float4* __restrict__ pts4,
                                                  u16* __restrict__ nbr) {
    __shared__ float4 ptsL[PCLD];          // 32 KB: drain re-reads only
    const int tid = threadIdx.x;
    const int cloud = blockIdx.x >> 3;
    const int qi = ((blockIdx.x & 7) << 8) + tid;   // local query idx
    const float4* __restrict__ pc = pts4 + ((u64)cloud << 11);

    for (int t = tid; t < PCLD; t += 256) ptsL[t] = pc[t];
    __syncthreads();

    const float4 q = ptsL[qi];
    const float qx = q.x, qy = q.y, qz = q.z, qs = q.w;

    u64 list[KNN];
#pragma unroll
    for (int k = 0; k < KNN; ++k) list[k] = 0xFF800000FFFFFFFFull;  // enc(+inf)
    float thr = __builtin_inff();

    float4 cur[8];
#pragma unroll
    for (int j = 0; j < 8; ++j) cur[j] = pc[j];   // wave-uniform loads

    for (int base = 0; base < PCLD; base += 64) {
        u64 mask = 0;
#pragma unroll
        for (int s = 0; s < 8; ++s) {
            const int nxtoff = (base + (s + 1) * 8) & (PCLD - 1);
            float4 nxt[8];
#pragma unroll
            for (int j = 0; j < 8; ++j) nxt[j] = pc[nxtoff + j];  // prefetch (uniform)
#pragma unroll
            for (int j = 0; j < 8; ++j) {
                const float cx = cur[j].x, cy = cur[j].y, cz = cur[j].z, cs = cur[j].w;
                float dot = __builtin_fmaf(cz, qz, __builtin_fmaf(cy, qy, __fmul_rn(cx, qx)));
                float d = __fsub_rn(__fadd_rn(qs, cs), __fmul_rn(2.0f, dot));
                if (d < thr) mask |= (1ull << (s * 8 + j));   // compile-time bit pos
            }
#pragma unroll
            for (int j = 0; j < 8; ++j) cur[j] = nxt[j];
        }
        while (mask) {
            int c = __builtin_ctzll(mask);
            mask &= mask - 1;
            float4 p2 = ptsL[base + c];
            float dot = __builtin_fmaf(p2.z, qz, __builtin_fmaf(p2.y, qy, __fmul_rn(p2.x, qx)));
            float d = __fsub_rn(__fadd_rn(qs, p2.w), __fmul_rn(2.0f, dot));
            if (d < thr) {   // thr may have tightened since mask was built
                u32 ub = __float_as_uint(d);
                u32 e = ub ^ ((u32)((int)ub >> 31) | 0x80000000u);  // monotone map
                u64 key = (((u64)e) << 32) | (u32)(base + c);
#pragma unroll
                for (int k = 0; k < KNN; ++k) {   // unrolled sorted insert
                    u64 lo = key < list[k] ? key : list[k];
                    u64 hi = key < list[k] ? list[k] : key;
                    list[k] = lo; key = hi;
                }
                u32 e19 = (u32)(list[KNN - 1] >> 32);
                thr = __uint_as_float(e19 ^ (0x80000000u | ~(u32)((int)e19 >> 31)));
            }
        }
    }

    u16* out = nbr + (u64)(cloud * PCLD + qi) * KNN;
#pragma unroll
    for (int k = 0; k < KNN; ++k) out[k] = (u16)(u32)list[k];  // local idx < 2048
}

// ---------------------------------------------------------------------------
// Transfer MLP: h0 = bf16(x @ Wt + bt), fp32 math
// ---------------------------------------------------------------------------
__global__ __launch_bounds__(256) void feat_kernel(const float* __restrict__ x,
                                                   const float* __restrict__ Wt,
                                                   const float* __restrict__ bt,
                                                   u16* __restrict__ h0) {
    int gid = blockIdx.x * 256 + threadIdx.x;   // N*64 threads, 2 channels each
    int i = gid >> 6;
    int c = (gid & 63) << 1;
    float x0 = x[3 * i], x1 = x[3 * i + 1], x2 = x[3 * i + 2];
    float a0 = bt[c]     + x0 * Wt[c]     + x1 * Wt[128 + c]     + x2 * Wt[256 + c];
    float a1 = bt[c + 1] + x0 * Wt[c + 1] + x1 * Wt[128 + c + 1] + x2 * Wt[256 + c + 1];
    ((u32*)h0)[gid] = ((u32)f2bf(a0)) | (((u32)f2bf(a1)) << 16);
}

// ---------------------------------------------------------------------------
// Fused GIN layer: gather-max (21 rows) -> GEMM1(128->256)+ReLU -> GEMM2(256->128)
// -> bias + BN(+ReLU) -> out (bf16 intermediate or fp32 final).
// Block = 256 thr (4 waves), 64 rows per block.
// ---------------------------------------------------------------------------
template <int RELU_OUT, int OUT_F32>
__global__ __launch_bounds__(256) void layer_kernel(
    const u16* __restrict__ hin, const u16* __restrict__ nbr,
    const u16* __restrict__ W1T, const float* __restrict__ b1,
    const u16* __restrict__ W2T, const float* __restrict__ b2,
    const float* __restrict__ g, const float* __restrict__ be,
    const float* __restrict__ rm, const float* __restrict__ rv,
    void* __restrict__ hout_v) {
    __shared__ u16 aggL[64][136];   // +8 pad: row stride 272B -> 2-way max (free)
    __shared__ u16 hidL[64][264];   // +8 pad: 528B row stride
    const int tid = threadIdx.x;
    const int R = blockIdx.x * 64;

    // ---- Phase A: gather-max over self + 20 neighbors (bf16-exact via fp32 max)
    {
        const int r = tid >> 2, cg = tid & 3;   // 64 rows x 4 channel groups of 32
        const int gr = R + r;
        const int c0 = cg << 5;
        const int cloudBase = (gr >> 11) << 11;   // cloud start row
        float m[32];
        const uint4* self4 = (const uint4*)(hin + (u64)gr * HD + c0);
#pragma unroll
        for (int q4 = 0; q4 < 4; ++q4) {
            uint4 v = self4[q4];
            u32 w[4] = {v.x, v.y, v.z, v.w};
#pragma unroll
            for (int d = 0; d < 4; ++d) {
                m[q4 * 8 + 2 * d]     = __uint_as_float(w[d] << 16);
                m[q4 * 8 + 2 * d + 1] = __uint_as_float(w[d] & 0xFFFF0000u);
            }
        }
        // preload all 20 neighbor ids (5 x u64; row stride 40B is 8B-aligned)
        const u64* nb8 = (const u64*)(nbr + (u64)gr * KNN);
        u64 nq[5];
#pragma unroll
        for (int w = 0; w < 5; ++w) nq[w] = nb8[w];
#pragma unroll 4
        for (int t = 0; t < KNN; ++t) {
            int loc = (int)(nq[t >> 2] >> ((t & 3) * 16)) & (PCLD - 1);
            int j = cloudBase + loc;
            const uint4* n4 = (const uint4*)(hin + (u64)j * HD + c0);
#pragma unroll
            for (int q4 = 0; q4 < 4; ++q4) {
                uint4 v = n4[q4];
                u32 w[4] = {v.x, v.y, v.z, v.w};
#pragma unroll
                for (int d = 0; d < 4; ++d) {
                    m[q4 * 8 + 2 * d]     = fmaxf(m[q4 * 8 + 2 * d],     __uint_as_float(w[d] << 16));
                    m[q4 * 8 + 2 * d + 1] = fmaxf(m[q4 * 8 + 2 * d + 1], __uint_as_float(w[d] & 0xFFFF0000u));
                }
            }
        }
        u32* dst = (u32*)&aggL[r][c0];
#pragma unroll
        for (int d = 0; d < 16; ++d)   // exact repack (max of bf16 values is bf16)
            dst[d] = (__float_as_uint(m[2 * d]) >> 16) | (__float_as_uint(m[2 * d + 1]) & 0xFFFF0000u);
    }
    __syncthreads();

    const int wv = tid >> 6, lane = tid & 63;
    const int lr = lane & 15;   // m-row / n-col within tile
    const int lq = lane >> 4;   // quad -> k chunk

    // ---- Phase B: hid = relu(agg @ W1 + b1) -> hidL  (wave owns 64 n-cols)
    {
        f32x4 acc[4][4];
#pragma unroll
        for (int i = 0; i < 4; ++i)
#pragma unroll
            for (int j = 0; j < 4; ++j) acc[i][j] = (f32x4)(0.0f);
        const int nb0 = wv * 64;
#pragma unroll
        for (int ks = 0; ks < 4; ++ks) {
            const int kcol = ks * 32 + lq * 8;
            bf16x8 af[4], bfr[4];
#pragma unroll
            for (int mt = 0; mt < 4; ++mt)
                af[mt] = *(const bf16x8*)&aggL[mt * 16 + lr][kcol];
#pragma unroll
            for (int nt = 0; nt < 4; ++nt)
                bfr[nt] = *(const bf16x8*)&W1T[(u64)(nb0 + nt * 16 + lr) * HD + kcol];
#pragma unroll
            for (int mt = 0; mt < 4; ++mt)
#pragma unroll
                for (int nt = 0; nt < 4; ++nt)
                    acc[mt][nt] = __builtin_amdgcn_mfma_f32_16x16x32_bf16(af[mt], bfr[nt], acc[mt][nt], 0, 0, 0);
        }
#pragma unroll
        for (int nt = 0; nt < 4; ++nt) {
            const int c = nb0 + nt * 16 + lr;
            const float bias = b1[c];
#pragma unroll
            for (int mt = 0; mt < 4; ++mt)
#pragma unroll
                for (int r2 = 0; r2 < 4; ++r2) {
                    float v = fmaxf(acc[mt][nt][r2] + bias, 0.0f);
                    hidL[mt * 16 + lq * 4 + r2][c] = f2bf(v);
                }
        }
    }
    __syncthreads();

    // ---- Phase C: out = BN(hid @ W2 + b2) (+ReLU) -> global  (wave owns 32 n-cols)
    {
        f32x4 acc[4][2];
#pragma unroll
        for (int i = 0; i < 4; ++i) { acc[i][0] = (f32x4)(0.0f); acc[i][1] = (f32x4)(0.0f); }
        const int nb0 = wv * 32;
#pragma unroll
        for (int ks = 0; ks < 8; ++ks) {
            const int kcol = ks * 32 + lq * 8;
            bf16x8 af[4], bfr[2];
#pragma unroll
            for (int mt = 0; mt < 4; ++mt)
                af[mt] = *(const bf16x8*)&hidL[mt * 16 + lr][kcol];
#pragma unroll
            for (int nt = 0; nt < 2; ++nt)
                bfr[nt] = *(const bf16x8*)&W2T[(u64)(nb0 + nt * 16 + lr) * HD2 + kcol];
#pragma unroll
            for (int mt = 0; mt < 4; ++mt)
#pragma unroll
                for (int nt = 0; nt < 2; ++nt)
                    acc[mt][nt] = __builtin_amdgcn_mfma_f32_16x16x32_bf16(af[mt], bfr[nt], acc[mt][nt], 0, 0, 0);
        }
#pragma unroll
        for (int nt = 0; nt < 2; ++nt) {
            const int c = nb0 + nt * 16 + lr;
            const float bias = b2[c];
            const float sc = g[c] * (1.0f / sqrtf(rv[c] + 1e-5f));
            const float rmc = rm[c];
            const float bec = be[c];
#pragma unroll
            for (int mt = 0; mt < 4; ++mt)
#pragma unroll
                for (int r2 = 0; r2 < 4; ++r2) {
                    float v = acc[mt][nt][r2] + bias;
                    v = (v - rmc) * sc + bec;
                    if (RELU_OUT) v = fmaxf(v, 0.0f);
                    const u64 oidx = (u64)(R + mt * 16 + lq * 4 + r2) * HD + c;
                    if (OUT_F32) ((float*)hout_v)[oidx] = v;
                    else         ((u16*)hout_v)[oidx] = f2bf(v);
                }
        }
    }
}

// ---------------------------------------------------------------------------
extern "C" void kernel_launch(void* const* d_in, const int* in_sizes, int n_in,
                              void* d_out, int out_size, void* d_ws, size_t ws_size,
                              hipStream_t stream) {
    const float* x    = (const float*)d_in[0];
    // d_in[1] = batch (int32, unused: clouds are contiguous, equal size)
    const float* Wt   = (const float*)d_in[2];
    const float* bt   = (const float*)d_in[3];
    const float* W1_0 = (const float*)d_in[4];
    const float* b1_0 = (const float*)d_in[5];
    const float* W2_0 = (const float*)d_in[6];
    const float* b2_0 = (const float*)d_in[7];
    const float* g0   = (const float*)d_in[8];
    const float* be0  = (const float*)d_in[9];
    const float* rm0  = (const float*)d_in[10];
    const float* rv0  = (const float*)d_in[11];
    const float* W1_1 = (const float*)d_in[12];
    const float* b1_1 = (const float*)d_in[13];
    const float* W2_1 = (const float*)d_in[14];
    const float* b2_1 = (const float*)d_in[15];
    const float* g1   = (const float*)d_in[16];
    const float* be1  = (const float*)d_in[17];
    const float* rm1  = (const float*)d_in[18];
    const float* rv1  = (const float*)d_in[19];

    char* ws = (char*)d_ws;
    u16* h0   = (u16*)ws;                                   // 16,777,216 B
    u16* h1   = (u16*)(ws + 16777216);                      // 16,777,216 B
    u16* W10T = (u16*)(ws + 2 * 16777216);                  // 65,536 B each
    u16* W20T = W10T + 32768;
    u16* W11T = W20T + 32768;
    u16* W21T = W11T + 32768;
    u16* nbr  = (u16*)(ws + 2 * 16777216 + 4 * 65536);      // N*20*2 = 2,621,440 B
    float4* pts4 = (float4*)(ws + 2 * 16777216 + 4 * 65536 + 2621440);  // 1 MB
    // total ws use ~38 MB

    pack_kernel<<<256, 256, 0, stream>>>(x, pts4);
    knn_kernel<<<256, 256, 0, stream>>>(pts4, nbr);
    prep_kernel<<<512, 256, 0, stream>>>(W1_0, W2_0, W1_1, W2_1, W10T, W20T, W11T, W21T);
    feat_kernel<<<16384, 256, 0, stream>>>(x, Wt, bt, h0);
    layer_kernel<1, 0><<<1024, 256, 0, stream>>>(h0, nbr, W10T, b1_0, W20T, b2_0,
                                                 g0, be0, rm0, rv0, h1);
    layer_kernel<0, 1><<<1024, 256, 0, stream>>>(h1, nbr, W11T, b1_1, W21T, b2_1,
                                                 g1, be1, rm1, rv1, d_out);
}

// Round 6
// 401.686 us; speedup vs baseline: 1.0184x; 1.0184x over previous
//
#include <hip/hip_runtime.h>

typedef unsigned int u32;
typedef unsigned short u16;
typedef unsigned long long u64;

// Problem constants
#define NPTS 65536
#define PCLD 2048
#define KNN 20
#define HD 128
#define HD2 256

typedef __attribute__((ext_vector_type(8))) short bf16x8;   // 8 bf16 = 4 VGPRs (A/B frag)
typedef __attribute__((ext_vector_type(4))) float f32x4;    // C/D frag

__device__ __forceinline__ float bf2f(u16 h) { return __uint_as_float(((u32)h) << 16); }
__device__ __forceinline__ u16 f2bf(float f) {
    u32 u = __float_as_uint(f);
    u32 r = (u + 0x7FFFu + ((u >> 16) & 1u)) >> 16;  // RNE
    return (u16)r;
}

// ---------------------------------------------------------------------------
// Weight prep: fp32 -> bf16 + transpose.
// ---------------------------------------------------------------------------
__global__ __launch_bounds__(256) void prep_kernel(
    const float* __restrict__ W1_0, const float* __restrict__ W2_0,
    const float* __restrict__ W1_1, const float* __restrict__ W2_1,
    u16* __restrict__ W1_0T, u16* __restrict__ W2_0T,
    u16* __restrict__ W1_1T, u16* __restrict__ W2_1T) {
    int id = blockIdx.x * 256 + threadIdx.x;   // 4 * 32768 threads
    int m = id >> 15, e = id & 32767;
    if (m == 0)      { int n = e >> 7, k = e & 127; W1_0T[e] = f2bf(W1_0[k * 256 + n]); }
    else if (m == 1) { int n = e >> 8, k = e & 255; W2_0T[e] = f2bf(W2_0[k * 128 + n]); }
    else if (m == 2) { int n = e >> 7, k = e & 127; W1_1T[e] = f2bf(W1_1[k * 256 + n]); }
    else             { int n = e >> 8, k = e & 255; W2_1T[e] = f2bf(W2_1[k * 128 + n]); }
}

// ---------------------------------------------------------------------------
// kNN v6 = R2 structure (best known: 155 us) with the readlane broadcast
// replaced by wave-uniform ds_read_b128 (same-address LDS read = HW
// broadcast, free): mask pass drops 13 -> 8 instr/candidate. Double-buffered
// 8-candidate chunks hide LDS latency in-wave. Divergent ctz-drain with
// exact u64 (dist,idx) sorted insert unchanged from R2.
// Distance replicates np fp32 op order:
//   sq = RN(RN(x^2+y^2)+z^2); dot = fma(z,zq, fma(y,yq, RN(x*xq)));
//   d  = RN(RN(sq_q+sq_c) - RN(2*dot))
// ---------------------------------------------------------------------------
__global__ __launch_bounds__(256) void knn_kernel(const float* __restrict__ x,
                                                  u16* __restrict__ nbr) {
    __shared__ float4 ptsL[PCLD];          // 32 KB
    const int tid = threadIdx.x;
    const int cloud = blockIdx.x >> 3;
    const int qi = ((blockIdx.x & 7) << 8) + tid;   // local query idx
    const float* __restrict__ xc = x + (u64)cloud * PCLD * 3;
    for (int t = tid; t < PCLD; t += 256) {         // fused pack: (x,y,z,sq)
        float a = xc[3 * t], b = xc[3 * t + 1], c = xc[3 * t + 2];
        float sq = __fadd_rn(__fadd_rn(__fmul_rn(a, a), __fmul_rn(b, b)), __fmul_rn(c, c));
        ptsL[t] = make_float4(a, b, c, sq);
    }
    __syncthreads();

    const float4 q = ptsL[qi];
    const float qx = q.x, qy = q.y, qz = q.z, qs = q.w;

    u64 list[KNN];
#pragma unroll
    for (int k = 0; k < KNN; ++k) list[k] = 0xFF800000FFFFFFFFull;  // enc(+inf)
    float thr = __builtin_inff();

    for (int base = 0; base < PCLD; base += 64) {
        u64 mask = 0;
        float4 buf[2][8];
#pragma unroll
        for (int j = 0; j < 8; ++j) buf[0][j] = ptsL[base + j];   // uniform addr: broadcast
#pragma unroll
        for (int s = 0; s < 8; ++s) {
            if (s < 7) {
#pragma unroll
                for (int j = 0; j < 8; ++j)
                    buf[(s + 1) & 1][j] = ptsL[base + (s + 1) * 8 + j];  // prefetch chunk
            }
#pragma unroll
            for (int j = 0; j < 8; ++j) {
                const float4 cp = buf[s & 1][j];
                float dot = __builtin_fmaf(cp.z, qz, __builtin_fmaf(cp.y, qy, __fmul_rn(cp.x, qx)));
                float d = __fsub_rn(__fadd_rn(qs, cp.w), __fmul_rn(2.0f, dot));
                if (d < thr) mask |= (1ull << (s * 8 + j));   // compile-time bit pos
            }
        }
        while (mask) {
            int c = __builtin_ctzll(mask);
            mask &= mask - 1;
            float4 p2 = ptsL[base + c];
            float dot = __builtin_fmaf(p2.z, qz, __builtin_fmaf(p2.y, qy, __fmul_rn(p2.x, qx)));
            float d = __fsub_rn(__fadd_rn(qs, p2.w), __fmul_rn(2.0f, dot));
            if (d < thr) {   // thr may have tightened since mask was built
                u32 ub = __float_as_uint(d);
                u32 e = ub ^ ((u32)((int)ub >> 31) | 0x80000000u);  // monotone map
                u64 key = (((u64)e) << 32) | (u32)(base + c);
#pragma unroll
                for (int k = 0; k < KNN; ++k) {   // unrolled sorted insert
                    u64 lo = key < list[k] ? key : list[k];
                    u64 hi = key < list[k] ? list[k] : key;
                    list[k] = lo; key = hi;
                }
                u32 e19 = (u32)(list[KNN - 1] >> 32);
                thr = __uint_as_float(e19 ^ (0x80000000u | ~(u32)((int)e19 >> 31)));
            }
        }
    }

    u16* out = nbr + (u64)(cloud * PCLD + qi) * KNN;
#pragma unroll
    for (int k = 0; k < KNN; ++k) out[k] = (u16)(u32)list[k];  // local idx < 2048
}

// ---------------------------------------------------------------------------
// Transfer MLP: h0 = bf16(x @ Wt + bt), fp32 math
// ---------------------------------------------------------------------------
__global__ __launch_bounds__(256) void feat_kernel(const float* __restrict__ x,
                                                   const float* __restrict__ Wt,
                                                   const float* __restrict__ bt,
                                                   u16* __restrict__ h0) {
    int gid = blockIdx.x * 256 + threadIdx.x;   // N*64 threads, 2 channels each
    int i = gid >> 6;
    int c = (gid & 63) << 1;
    float x0 = x[3 * i], x1 = x[3 * i + 1], x2 = x[3 * i + 2];
    float a0 = bt[c]     + x0 * Wt[c]     + x1 * Wt[128 + c]     + x2 * Wt[256 + c];
    float a1 = bt[c + 1] + x0 * Wt[c + 1] + x1 * Wt[128 + c + 1] + x2 * Wt[256 + c + 1];
    ((u32*)h0)[gid] = ((u32)f2bf(a0)) | (((u32)f2bf(a1)) << 16);
}

// ---------------------------------------------------------------------------
// Fused GIN layer: gather-max (21 rows) -> GEMM1(128->256)+ReLU -> GEMM2(256->128)
// -> bias + BN(+ReLU) -> out (bf16 intermediate or fp32 final).
// Block = 256 thr (4 waves), 64 rows per block.
// ---------------------------------------------------------------------------
template <int RELU_OUT, int OUT_F32>
__global__ __launch_bounds__(256) void layer_kernel(
    const u16* __restrict__ hin, const u16* __restrict__ nbr,
    const u16* __restrict__ W1T, const float* __restrict__ b1,
    const u16* __restrict__ W2T, const float* __restrict__ b2,
    const float* __restrict__ g, const float* __restrict__ be,
    const float* __restrict__ rm, const float* __restrict__ rv,
    void* __restrict__ hout_v) {
    __shared__ u16 aggL[64][136];   // +8 pad: row stride 272B -> 2-way max (free)
    __shared__ u16 hidL[64][264];   // +8 pad: 528B row stride
    const int tid = threadIdx.x;
    const int R = blockIdx.x * 64;

    // ---- Phase A: gather-max over self + 20 neighbors (bf16-exact via fp32 max)
    {
        const int r = tid >> 2, cg = tid & 3;   // 64 rows x 4 channel groups of 32
        const int gr = R + r;
        const int c0 = cg << 5;
        const int cloudBase = (gr >> 11) << 11;   // cloud start row
        float m[32];
        const uint4* self4 = (const uint4*)(hin + (u64)gr * HD + c0);
#pragma unroll
        for (int q4 = 0; q4 < 4; ++q4) {
            uint4 v = self4[q4];
            u32 w[4] = {v.x, v.y, v.z, v.w};
#pragma unroll
            for (int d = 0; d < 4; ++d) {
                m[q4 * 8 + 2 * d]     = __uint_as_float(w[d] << 16);
                m[q4 * 8 + 2 * d + 1] = __uint_as_float(w[d] & 0xFFFF0000u);
            }
        }
        // preload all 20 neighbor ids (5 x u64; row stride 40B is 8B-aligned)
        const u64* nb8 = (const u64*)(nbr + (u64)gr * KNN);
        u64 nq[5];
#pragma unroll
        for (int w = 0; w < 5; ++w) nq[w] = nb8[w];
#pragma unroll 4
        for (int t = 0; t < KNN; ++t) {
            int loc = (int)(nq[t >> 2] >> ((t & 3) * 16)) & (PCLD - 1);
            int j = cloudBase + loc;
            const uint4* n4 = (const uint4*)(hin + (u64)j * HD + c0);
#pragma unroll
            for (int q4 = 0; q4 < 4; ++q4) {
                uint4 v = n4[q4];
                u32 w[4] = {v.x, v.y, v.z, v.w};
#pragma unroll
                for (int d = 0; d < 4; ++d) {
                    m[q4 * 8 + 2 * d]     = fmaxf(m[q4 * 8 + 2 * d],     __uint_as_float(w[d] << 16));
                    m[q4 * 8 + 2 * d + 1] = fmaxf(m[q4 * 8 + 2 * d + 1], __uint_as_float(w[d] & 0xFFFF0000u));
                }
            }
        }
        u32* dst = (u32*)&aggL[r][c0];
#pragma unroll
        for (int d = 0; d < 16; ++d)   // exact repack (max of bf16 values is bf16)
            dst[d] = (__float_as_uint(m[2 * d]) >> 16) | (__float_as_uint(m[2 * d + 1]) & 0xFFFF0000u);
    }
    __syncthreads();

    const int wv = tid >> 6, lane = tid & 63;
    const int lr = lane & 15;   // m-row / n-col within tile
    const int lq = lane >> 4;   // quad -> k chunk

    // ---- Phase B: hid = relu(agg @ W1 + b1) -> hidL  (wave owns 64 n-cols)
    {
        f32x4 acc[4][4];
#pragma unroll
        for (int i = 0; i < 4; ++i)
#pragma unroll
            for (int j = 0; j < 4; ++j) acc[i][j] = (f32x4)(0.0f);
        const int nb0 = wv * 64;
#pragma unroll
        for (int ks = 0; ks < 4; ++ks) {
            const int kcol = ks * 32 + lq * 8;
            bf16x8 af[4], bfr[4];
#pragma unroll
            for (int mt = 0; mt < 4; ++mt)
                af[mt] = *(const bf16x8*)&aggL[mt * 16 + lr][kcol];
#pragma unroll
            for (int nt = 0; nt < 4; ++nt)
                bfr[nt] = *(const bf16x8*)&W1T[(u64)(nb0 + nt * 16 + lr) * HD + kcol];
#pragma unroll
            for (int mt = 0; mt < 4; ++mt)
#pragma unroll
                for (int nt = 0; nt < 4; ++nt)
                    acc[mt][nt] = __builtin_amdgcn_mfma_f32_16x16x32_bf16(af[mt], bfr[nt], acc[mt][nt], 0, 0, 0);
        }
#pragma unroll
        for (int nt = 0; nt < 4; ++nt) {
            const int c = nb0 + nt * 16 + lr;
            const float bias = b1[c];
#pragma unroll
            for (int mt = 0; mt < 4; ++mt)
#pragma unroll
                for (int r2 = 0; r2 < 4; ++r2) {
                    float v = fmaxf(acc[mt][nt][r2] + bias, 0.0f);
                    hidL[mt * 16 + lq * 4 + r2][c] = f2bf(v);
                }
        }
    }
    __syncthreads();

    // ---- Phase C: out = BN(hid @ W2 + b2) (+ReLU) -> global  (wave owns 32 n-cols)
    {
        f32x4 acc[4][2];
#pragma unroll
        for (int i = 0; i < 4; ++i) { acc[i][0] = (f32x4)(0.0f); acc[i][1] = (f32x4)(0.0f); }
        const int nb0 = wv * 32;
#pragma unroll
        for (int ks = 0; ks < 8; ++ks) {
            const int kcol = ks * 32 + lq * 8;
            bf16x8 af[4], bfr[2];
#pragma unroll
            for (int mt = 0; mt < 4; ++mt)
                af[mt] = *(const bf16x8*)&hidL[mt * 16 + lr][kcol];
#pragma unroll
            for (int nt = 0; nt < 2; ++nt)
                bfr[nt] = *(const bf16x8*)&W2T[(u64)(nb0 + nt * 16 + lr) * HD2 + kcol];
#pragma unroll
            for (int mt = 0; mt < 4; ++mt)
#pragma unroll
                for (int nt = 0; nt < 2; ++nt)
                    acc[mt][nt] = __builtin_amdgcn_mfma_f32_16x16x32_bf16(af[mt], bfr[nt], acc[mt][nt], 0, 0, 0);
        }
#pragma unroll
        for (int nt = 0; nt < 2; ++nt) {
            const int c = nb0 + nt * 16 + lr;
            const float bias = b2[c];
            const float sc = g[c] * (1.0f / sqrtf(rv[c] + 1e-5f));
            const float rmc = rm[c];
            const float bec = be[c];
#pragma unroll
            for (int mt = 0; mt < 4; ++mt)
#pragma unroll
                for (int r2 = 0; r2 < 4; ++r2) {
                    float v = acc[mt][nt][r2] + bias;
                    v = (v - rmc) * sc + bec;
                    if (RELU_OUT) v = fmaxf(v, 0.0f);
                    const u64 oidx = (u64)(R + mt * 16 + lq * 4 + r2) * HD + c;
                    if (OUT_F32) ((float*)hout_v)[oidx] = v;
                    else         ((u16*)hout_v)[oidx] = f2bf(v);
                }
        }
    }
}

// ---------------------------------------------------------------------------
extern "C" void kernel_launch(void* const* d_in, const int* in_sizes, int n_in,
                              void* d_out, int out_size, void* d_ws, size_t ws_size,
                              hipStream_t stream) {
    const float* x    = (const float*)d_in[0];
    // d_in[1] = batch (int32, unused: clouds are contiguous, equal size)
    const float* Wt   = (const float*)d_in[2];
    const float* bt   = (const float*)d_in[3];
    const float* W1_0 = (const float*)d_in[4];
    const float* b1_0 = (const float*)d_in[5];
    const float* W2_0 = (const float*)d_in[6];
    const float* b2_0 = (const float*)d_in[7];
    const float* g0   = (const float*)d_in[8];
    const float* be0  = (const float*)d_in[9];
    const float* rm0  = (const float*)d_in[10];
    const float* rv0  = (const float*)d_in[11];
    const float* W1_1 = (const float*)d_in[12];
    const float* b1_1 = (const float*)d_in[13];
    const float* W2_1 = (const float*)d_in[14];
    const float* b2_1 = (const float*)d_in[15];
    const float* g1   = (const float*)d_in[16];
    const float* be1  = (const float*)d_in[17];
    const float* rm1  = (const float*)d_in[18];
    const float* rv1  = (const float*)d_in[19];

    char* ws = (char*)d_ws;
    u16* h0   = (u16*)ws;                                   // 16,777,216 B
    u16* h1   = (u16*)(ws + 16777216);                      // 16,777,216 B
    u16* W10T = (u16*)(ws + 2 * 16777216);                  // 65,536 B each
    u16* W20T = W10T + 32768;
    u16* W11T = W20T + 32768;
    u16* W21T = W11T + 32768;
    u16* nbr  = (u16*)(ws + 2 * 16777216 + 4 * 65536);      // N*20*2 = 2,621,440 B
    // total ws use ~36.9 MB

    knn_kernel<<<256, 256, 0, stream>>>(x, nbr);
    prep_kernel<<<512, 256, 0, stream>>>(W1_0, W2_0, W1_1, W2_1, W10T, W20T, W11T, W21T);
    feat_kernel<<<16384, 256, 0, stream>>>(x, Wt, bt, h0);
    layer_kernel<1, 0><<<1024, 256, 0, stream>>>(h0, nbr, W10T, b1_0, W20T, b2_0,
                                                 g0, be0, rm0, rv0, h1);
    layer_kernel<0, 1><<<1024, 256, 0, stream>>>(h1, nbr, W11T, b1_1, W21T, b2_1,
                                                 g1, be1, rm1, rv1, d_out);
}

// Round 7
// 351.369 us; speedup vs baseline: 1.1642x; 1.1432x over previous
//
#include <hip/hip_runtime.h>

typedef unsigned int u32;
typedef unsigned short u16;
typedef unsigned long long u64;

// Problem constants
#define NPTS 65536
#define PCLD 2048
#define KNN 20
#define HD 128
#define HD2 256

typedef __attribute__((ext_vector_type(8))) short bf16x8;   // 8 bf16 = 4 VGPRs (A/B frag)
typedef __attribute__((ext_vector_type(4))) float f32x4;    // C/D frag

__device__ __forceinline__ float bf2f(u16 h) { return __uint_as_float(((u32)h) << 16); }
__device__ __forceinline__ u16 f2bf(float f) {
    u32 u = __float_as_uint(f);
    u32 r = (u + 0x7FFFu + ((u >> 16) & 1u)) >> 16;  // RNE
    return (u16)r;
}

// ---------------------------------------------------------------------------
// Weight prep: fp32 -> bf16 + transpose.
// ---------------------------------------------------------------------------
__global__ __launch_bounds__(256) void prep_kernel(
    const float* __restrict__ W1_0, const float* __restrict__ W2_0,
    const float* __restrict__ W1_1, const float* __restrict__ W2_1,
    u16* __restrict__ W1_0T, u16* __restrict__ W2_0T,
    u16* __restrict__ W1_1T, u16* __restrict__ W2_1T) {
    int id = blockIdx.x * 256 + threadIdx.x;   // 4 * 32768 threads
    int m = id >> 15, e = id & 32767;
    if (m == 0)      { int n = e >> 7, k = e & 127; W1_0T[e] = f2bf(W1_0[k * 256 + n]); }
    else if (m == 1) { int n = e >> 8, k = e & 255; W2_0T[e] = f2bf(W2_0[k * 128 + n]); }
    else if (m == 2) { int n = e >> 7, k = e & 127; W1_1T[e] = f2bf(W1_1[k * 256 + n]); }
    else             { int n = e >> 8, k = e & 255; W2_1T[e] = f2bf(W2_1[k * 128 + n]); }
}

// ---------------------------------------------------------------------------
// kNN — EXACT R2 structure (empirical best: 155 us; do not modify).
// 8 blocks per cloud, 1 thread = 1 query. Cloud (x,y,z,sq) in LDS; wave
// loads 64 candidates (1 ds_read_b128/lane) then broadcasts via readlane.
// Divergent ctz-drain re-reads LDS + recomputes d. Top-20 kept as sorted
// u64 (monotone dist | idx) keys -> exact top_k tie semantics.
// Distance replicates np fp32 op order.
// ---------------------------------------------------------------------------
__global__ __launch_bounds__(256) void knn_kernel(const float* __restrict__ x,
                                                  u16* __restrict__ nbr) {
    __shared__ float4 pts[PCLD];
    const int cloud = blockIdx.x >> 3;
    const int qi = ((blockIdx.x & 7) << 8) + threadIdx.x;   // local query idx
    const float* xc = x + (u64)cloud * PCLD * 3;
    for (int t = threadIdx.x; t < PCLD; t += 256) {
        float a = xc[3 * t], b = xc[3 * t + 1], c = xc[3 * t + 2];
        float sq = __fadd_rn(__fadd_rn(__fmul_rn(a, a), __fmul_rn(b, b)), __fmul_rn(c, c));
        pts[t] = make_float4(a, b, c, sq);
    }
    __syncthreads();
    const float4 q = pts[qi];
    const float qx = q.x, qy = q.y, qz = q.z, qs = q.w;
    const int lane = threadIdx.x & 63;
    u64 list[KNN];
#pragma unroll
    for (int k = 0; k < KNN; ++k) list[k] = 0xFF800000FFFFFFFFull;  // enc(+inf)
    float thr = __builtin_inff();

    for (int base = 0; base < PCLD; base += 64) {
        float4 cp = pts[base + lane];   // 1 ds_read_b128 per 64 candidates
        u64 mask = 0;
#pragma unroll
        for (int c = 0; c < 64; ++c) {
            float cx = __uint_as_float(__builtin_amdgcn_readlane(__float_as_uint(cp.x), c));
            float cy = __uint_as_float(__builtin_amdgcn_readlane(__float_as_uint(cp.y), c));
            float cz = __uint_as_float(__builtin_amdgcn_readlane(__float_as_uint(cp.z), c));
            float cs = __uint_as_float(__builtin_amdgcn_readlane(__float_as_uint(cp.w), c));
            float dot = __builtin_fmaf(cz, qz, __builtin_fmaf(cy, qy, __fmul_rn(cx, qx)));
            float d = __fsub_rn(__fadd_rn(qs, cs), __fmul_rn(2.0f, dot));
            if (d < thr) mask |= (1ull << c);
        }
        while (mask) {
            int c = __builtin_ctzll(mask);
            mask &= mask - 1;
            float4 p2 = pts[base + c];
            float dot = __builtin_fmaf(p2.z, qz, __builtin_fmaf(p2.y, qy, __fmul_rn(p2.x, qx)));
            float d = __fsub_rn(__fadd_rn(qs, p2.w), __fmul_rn(2.0f, dot));
            if (d < thr) {   // thr may have tightened since mask was built
                u32 ub = __float_as_uint(d);
                u32 e = (ub & 0x80000000u) ? ~ub : (ub | 0x80000000u);  // monotone map
                u64 key = (((u64)e) << 32) | (u32)(base + c);
#pragma unroll
                for (int k = 0; k < KNN; ++k) {   // unrolled sorted insert
                    u64 lo = key < list[k] ? key : list[k];
                    u64 hi = key < list[k] ? list[k] : key;
                    list[k] = lo; key = hi;
                }
                u32 e19 = (u32)(list[KNN - 1] >> 32);
                u32 ud = (e19 & 0x80000000u) ? (e19 & 0x7FFFFFFFu) : ~e19;
                thr = __uint_as_float(ud);
            }
        }
    }
    u16* out = nbr + (u64)(cloud * PCLD + qi) * KNN;
#pragma unroll
    for (int k = 0; k < KNN; ++k) out[k] = (u16)(u32)list[k];  // local idx < 2048
}

// ---------------------------------------------------------------------------
// Transfer MLP: h0 = bf16(x @ Wt + bt), fp32 math
// ---------------------------------------------------------------------------
__global__ __launch_bounds__(256) void feat_kernel(const float* __restrict__ x,
                                                   const float* __restrict__ Wt,
                                                   const float* __restrict__ bt,
                                                   u16* __restrict__ h0) {
    int gid = blockIdx.x * 256 + threadIdx.x;   // N*64 threads, 2 channels each
    int i = gid >> 6;
    int c = (gid & 63) << 1;
    float x0 = x[3 * i], x1 = x[3 * i + 1], x2 = x[3 * i + 2];
    float a0 = bt[c]     + x0 * Wt[c]     + x1 * Wt[128 + c]     + x2 * Wt[256 + c];
    float a1 = bt[c + 1] + x0 * Wt[c + 1] + x1 * Wt[128 + c + 1] + x2 * Wt[256 + c + 1];
    ((u32*)h0)[gid] = ((u32)f2bf(a0)) | (((u32)f2bf(a1)) << 16);
}

// ---------------------------------------------------------------------------
// Fused GIN layer: gather-max (21 rows) -> GEMM1(128->256)+ReLU -> GEMM2(256->128)
// -> bias + BN(+ReLU) -> out (bf16 intermediate or fp32 final).
// Block = 256 thr (4 waves), 64 rows per block.
// XCD swizzle: all 32 blocks of a cloud land on ONE XCD (blockIdx%8 = XCD on
// MI355X round-robin dispatch) -> each XCD L2 caches only its 4 clouds
// (4 x 512KB = 2MB < 4MiB), killing cross-XCD h re-fetch.
// ---------------------------------------------------------------------------
template <int RELU_OUT, int OUT_F32>
__global__ __launch_bounds__(256) void layer_kernel(
    const u16* __restrict__ hin, const u16* __restrict__ nbr,
    const u16* __restrict__ W1T, const float* __restrict__ b1,
    const u16* __restrict__ W2T, const float* __restrict__ b2,
    const float* __restrict__ g, const float* __restrict__ be,
    const float* __restrict__ rm, const float* __restrict__ rv,
    void* __restrict__ hout_v) {
    __shared__ u16 aggL[64][136];   // +8 pad: row stride 272B -> 2-way max (free)
    __shared__ u16 hidL[64][264];   // +8 pad: 528B row stride
    const int tid = threadIdx.x;
    // XCD-aware mapping: physical block p -> (cloud, sub)
    const int p = blockIdx.x;
    const int xcd = p & 7;
    const int w = p >> 3;                 // 0..127 within XCD
    const int cloudI = xcd * 4 + (w >> 5);   // 4 clouds per XCD
    const int sub = w & 31;                  // 32 blocks per cloud
    const int R = cloudI * PCLD + sub * 64;

    // ---- Phase A: gather-max over self + 20 neighbors (bf16-exact via fp32 max)
    {
        const int r = tid >> 2, cg = tid & 3;   // 64 rows x 4 channel groups of 32
        const int gr = R + r;
        const int c0 = cg << 5;
        const int cloudBase = cloudI << 11;     // cloud start row
        float m[32];
        const uint4* self4 = (const uint4*)(hin + (u64)gr * HD + c0);
#pragma unroll
        for (int q4 = 0; q4 < 4; ++q4) {
            uint4 v = self4[q4];
            u32 w2[4] = {v.x, v.y, v.z, v.w};
#pragma unroll
            for (int d = 0; d < 4; ++d) {
                m[q4 * 8 + 2 * d]     = __uint_as_float(w2[d] << 16);
                m[q4 * 8 + 2 * d + 1] = __uint_as_float(w2[d] & 0xFFFF0000u);
            }
        }
        // preload all 20 neighbor ids (5 x u64; row stride 40B is 8B-aligned)
        const u64* nb8 = (const u64*)(nbr + (u64)gr * KNN);
        u64 nq[5];
#pragma unroll
        for (int w3 = 0; w3 < 5; ++w3) nq[w3] = nb8[w3];
#pragma unroll 4
        for (int t = 0; t < KNN; ++t) {
            int loc = (int)(nq[t >> 2] >> ((t & 3) * 16)) & (PCLD - 1);
            int j = cloudBase + loc;
            const uint4* n4 = (const uint4*)(hin + (u64)j * HD + c0);
#pragma unroll
            for (int q4 = 0; q4 < 4; ++q4) {
                uint4 v = n4[q4];
                u32 w2[4] = {v.x, v.y, v.z, v.w};
#pragma unroll
                for (int d = 0; d < 4; ++d) {
                    m[q4 * 8 + 2 * d]     = fmaxf(m[q4 * 8 + 2 * d],     __uint_as_float(w2[d] << 16));
                    m[q4 * 8 + 2 * d + 1] = fmaxf(m[q4 * 8 + 2 * d + 1], __uint_as_float(w2[d] & 0xFFFF0000u));
                }
            }
        }
        u32* dst = (u32*)&aggL[r][c0];
#pragma unroll
        for (int d = 0; d < 16; ++d)   // exact repack (max of bf16 values is bf16)
            dst[d] = (__float_as_uint(m[2 * d]) >> 16) | (__float_as_uint(m[2 * d + 1]) & 0xFFFF0000u);
    }
    __syncthreads();

    const int wv = tid >> 6, lane = tid & 63;
    const int lr = lane & 15;   // m-row / n-col within tile
    const int lq = lane >> 4;   // quad -> k chunk

    // ---- Phase B: hid = relu(agg @ W1 + b1) -> hidL  (wave owns 64 n-cols)
    {
        f32x4 acc[4][4];
#pragma unroll
        for (int i = 0; i < 4; ++i)
#pragma unroll
            for (int j = 0; j < 4; ++j) acc[i][j] = (f32x4)(0.0f);
        const int nb0 = wv * 64;
#pragma unroll
        for (int ks = 0; ks < 4; ++ks) {
            const int kcol = ks * 32 + lq * 8;
            bf16x8 af[4], bfr[4];
#pragma unroll
            for (int mt = 0; mt < 4; ++mt)
                af[mt] = *(const bf16x8*)&aggL[mt * 16 + lr][kcol];
#pragma unroll
            for (int nt = 0; nt < 4; ++nt)
                bfr[nt] = *(const bf16x8*)&W1T[(u64)(nb0 + nt * 16 + lr) * HD + kcol];
#pragma unroll
            for (int mt = 0; mt < 4; ++mt)
#pragma unroll
                for (int nt = 0; nt < 4; ++nt)
                    acc[mt][nt] = __builtin_amdgcn_mfma_f32_16x16x32_bf16(af[mt], bfr[nt], acc[mt][nt], 0, 0, 0);
        }
#pragma unroll
        for (int nt = 0; nt < 4; ++nt) {
            const int c = nb0 + nt * 16 + lr;
            const float bias = b1[c];
#pragma unroll
            for (int mt = 0; mt < 4; ++mt)
#pragma unroll
                for (int r2 = 0; r2 < 4; ++r2) {
                    float v = fmaxf(acc[mt][nt][r2] + bias, 0.0f);
                    hidL[mt * 16 + lq * 4 + r2][c] = f2bf(v);
                }
        }
    }
    __syncthreads();

    // ---- Phase C: out = BN(hid @ W2 + b2) (+ReLU) -> global  (wave owns 32 n-cols)
    {
        f32x4 acc[4][2];
#pragma unroll
        for (int i = 0; i < 4; ++i) { acc[i][0] = (f32x4)(0.0f); acc[i][1] = (f32x4)(0.0f); }
        const int nb0 = wv * 32;
#pragma unroll
        for (int ks = 0; ks < 8; ++ks) {
            const int kcol = ks * 32 + lq * 8;
            bf16x8 af[4], bfr[2];
#pragma unroll
            for (int mt = 0; mt < 4; ++mt)
                af[mt] = *(const bf16x8*)&hidL[mt * 16 + lr][kcol];
#pragma unroll
            for (int nt = 0; nt < 2; ++nt)
                bfr[nt] = *(const bf16x8*)&W2T[(u64)(nb0 + nt * 16 + lr) * HD2 + kcol];
#pragma unroll
            for (int mt = 0; mt < 4; ++mt)
#pragma unroll
                for (int nt = 0; nt < 2; ++nt)
                    acc[mt][nt] = __builtin_amdgcn_mfma_f32_16x16x32_bf16(af[mt], bfr[nt], acc[mt][nt], 0, 0, 0);
        }
#pragma unroll
        for (int nt = 0; nt < 2; ++nt) {
            const int c = nb0 + nt * 16 + lr;
            const float bias = b2[c];
            const float sc = g[c] * (1.0f / sqrtf(rv[c] + 1e-5f));
            const float rmc = rm[c];
            const float bec = be[c];
#pragma unroll
            for (int mt = 0; mt < 4; ++mt)
#pragma unroll
                for (int r2 = 0; r2 < 4; ++r2) {
                    float v = acc[mt][nt][r2] + bias;
                    v = (v - rmc) * sc + bec;
                    if (RELU_OUT) v = fmaxf(v, 0.0f);
                    const u64 oidx = (u64)(R + mt * 16 + lq * 4 + r2) * HD + c;
                    if (OUT_F32) ((float*)hout_v)[oidx] = v;
                    else         ((u16*)hout_v)[oidx] = f2bf(v);
                }
        }
    }
}

// ---------------------------------------------------------------------------
extern "C" void kernel_launch(void* const* d_in, const int* in_sizes, int n_in,
                              void* d_out, int out_size, void* d_ws, size_t ws_size,
                              hipStream_t stream) {
    const float* x    = (const float*)d_in[0];
    // d_in[1] = batch (int32, unused: clouds are contiguous, equal size)
    const float* Wt   = (const float*)d_in[2];
    const float* bt   = (const float*)d_in[3];
    const float* W1_0 = (const float*)d_in[4];
    const float* b1_0 = (const float*)d_in[5];
    const float* W2_0 = (const float*)d_in[6];
    const float* b2_0 = (const float*)d_in[7];
    const float* g0   = (const float*)d_in[8];
    const float* be0  = (const float*)d_in[9];
    const float* rm0  = (const float*)d_in[10];
    const float* rv0  = (const float*)d_in[11];
    const float* W1_1 = (const float*)d_in[12];
    const float* b1_1 = (const float*)d_in[13];
    const float* W2_1 = (const float*)d_in[14];
    const float* b2_1 = (const float*)d_in[15];
    const float* g1   = (const float*)d_in[16];
    const float* be1  = (const float*)d_in[17];
    const float* rm1  = (const float*)d_in[18];
    const float* rv1  = (const float*)d_in[19];

    char* ws = (char*)d_ws;
    u16* h0   = (u16*)ws;                                   // 16,777,216 B
    u16* h1   = (u16*)(ws + 16777216);                      // 16,777,216 B
    u16* W10T = (u16*)(ws + 2 * 16777216);                  // 65,536 B each
    u16* W20T = W10T + 32768;
    u16* W11T = W20T + 32768;
    u16* W21T = W11T + 32768;
    u16* nbr  = (u16*)(ws + 2 * 16777216 + 4 * 65536);      // N*20*2 = 2,621,440 B
    // total ws use ~36.9 MB

    knn_kernel<<<256, 256, 0, stream>>>(x, nbr);
    prep_kernel<<<512, 256, 0, stream>>>(W1_0, W2_0, W1_1, W2_1, W10T, W20T, W11T, W21T);
    feat_kernel<<<16384, 256, 0, stream>>>(x, Wt, bt, h0);
    layer_kernel<1, 0><<<1024, 256, 0, stream>>>(h0, nbr, W10T, b1_0, W20T, b2_0,
                                                 g0, be0, rm0, rv0, h1);
    layer_kernel<0, 1><<<1024, 256, 0, stream>>>(h1, nbr, W11T, b1_1, W21T, b2_1,
                                                 g1, be1, rm1, rv1, d_out);
}